// Round 2
// baseline (304.006 us; speedup 1.0000x reference)
//
#include <hip/hip_runtime.h>
#include <cstdint>
#include <cstddef>

typedef unsigned short u16;
typedef __attribute__((ext_vector_type(4))) float f32x4;
typedef __attribute__((ext_vector_type(8))) _Float16 f16x8;  // 8 f16 in 4 VGPRs
typedef __attribute__((ext_vector_type(4))) u16   u16x4;
typedef __attribute__((ext_vector_type(8))) u16   u16x8;

#define DEV static __device__ __forceinline__
#define MFMA16(a,b,c) __builtin_amdgcn_mfma_f32_16x16x32_f16((a),(b),(c),0,0,0)

constexpr int Bc = 4, Cc = 256, Nc = 2048, Hc = 8, Dc = 256, OCc = 2048;

// workspace layout (bytes)
constexpr size_t OFF_XT = 0;                                   // (B,N,C) f16
constexpr size_t OFF_YT = OFF_XT + (size_t)Bc*Nc*Cc*2;
constexpr size_t OFF_WQ = OFF_YT + (size_t)Bc*Nc*Cc*2;         // (OC,C) f16, g-folded
constexpr size_t OFF_WK = OFF_WQ + (size_t)OCc*Cc*2;
constexpr size_t OFF_WV = OFF_WK + (size_t)OCc*Cc*2;
constexpr size_t OFF_BQ = OFF_WV + (size_t)OCc*Cc*2;           // f32 bias (g*b+beta)
constexpr size_t OFF_BK = OFF_BQ + (size_t)OCc*4;
constexpr size_t OFF_BV = OFF_BK + (size_t)OCc*4;
constexpr size_t OFF_Q  = OFF_BV + (size_t)OCc*4;              // (B,H,N,D) f16
constexpr size_t OFF_K  = OFF_Q  + (size_t)Bc*Hc*Nc*Dc*2;      // (B,H,N,D) f16
constexpr size_t OFF_V  = OFF_K  + (size_t)Bc*Hc*Nc*Dc*2;      // (B,H,D,N) f16 (pre-transposed)

DEV u16 f2h(float x){                       // RNE f32 -> f16 bits
  _Float16 h = (_Float16)x;
  return __builtin_bit_cast(u16, h);
}

DEV void load_lds16(const void* g, void* l){
  __builtin_amdgcn_global_load_lds((const __attribute__((address_space(1))) int*)g,
                                   (__attribute__((address_space(3))) int*)l, 16, 0, 0);
}

// ---------------- kernel 0a: transpose + cast x,y -> X^T f16 (B,N,C) ----------------
__global__ __launch_bounds__(256) void transpose_cast(const float* __restrict__ x,
                                                      const float* __restrict__ y,
                                                      u16* __restrict__ XT,
                                                      u16* __restrict__ YT){
  __shared__ u16 tile[64][65];
  int b = blockIdx.z >> 1;
  const float* src = (blockIdx.z & 1) ? y : x;
  u16* dst = (blockIdx.z & 1) ? YT : XT;
  int n0 = blockIdx.x * 64, c0 = blockIdx.y * 64;
  int t = threadIdx.x;
#pragma unroll
  for (int i = 0; i < 16; ++i){
    int slot = i*256 + t;
    int cl = slot >> 6, nl = slot & 63;
    tile[cl][nl] = f2h(src[((size_t)b*Cc + c0 + cl)*Nc + n0 + nl]);
  }
  __syncthreads();
#pragma unroll
  for (int i = 0; i < 8; ++i){
    int slot = i*256 + t;
    int nl = slot >> 5, cl = (slot & 31)*2;
    uint32_t v = (uint32_t)tile[cl][nl] | ((uint32_t)tile[cl+1][nl] << 16);
    *(uint32_t*)(dst + ((size_t)b*Nc + n0 + nl)*Cc + c0 + cl) = v;
  }
}

// ---------------- kernel 0b: fold g into W (f16), bias = g*b+beta ----------------
__global__ __launch_bounds__(256) void prep_w(const float* __restrict__ W,
                                              const float* __restrict__ bsrc,
                                              const float* __restrict__ g,
                                              const float* __restrict__ beta,
                                              u16* __restrict__ Wo,
                                              float* __restrict__ bb){
  int idx = (blockIdx.x*256 + threadIdx.x) * 8;   // over OC*C
  int o = idx >> 8, c = idx & 255;
  float gg = g[o];
  f32x4 a0 = *(const f32x4*)(W + idx);
  f32x4 a1 = *(const f32x4*)(W + idx + 4);
  u16x8 r;
#pragma unroll
  for (int i = 0; i < 4; ++i){ r[i] = f2h(a0[i]*gg); r[i+4] = f2h(a1[i]*gg); }
  *(u16x8*)(Wo + idx) = r;
  if (c == 0) bb[o] = gg*bsrc[o] + beta[o];
}

// ---------------- kernel 1: projection GEMM ----------------
// SW=0 (Q,K): Z = W'·X, writes (B,H,N,D).  SW=1 (V): Z^T tiles, writes (B,H,D,N).
template<int SW>
__global__ __launch_bounds__(256, 2) void proj_gemm(const u16* __restrict__ Xt,
                                                    const u16* __restrict__ Wp,
                                                    const float* __restrict__ bb,
                                                    u16* __restrict__ outp){
  __shared__ __align__(16) char lds[32768];  // chunks: W kc0,kc1 @0,8K; X kc0,kc1 @16K,24K
  int t = threadIdx.x, w = t >> 6, l = t & 63, q = l & 15, g = l >> 4;
  int b = blockIdx.z;
  int n0 = blockIdx.x * 128, o0 = blockIdx.y * 128;
  f32x4 acc[4][4] = {};

  for (int it = 0; it < 4; ++it){
    __syncthreads();
#pragma unroll
    for (int j = 0; j < 8; ++j){
      int s = j*4 + w;                 // 0..31
      int chunk = s >> 3;              // 0,1 = W kc; 2,3 = X kc
      int off = (s & 7) * 1024;
      int row = (s & 7)*16 + (l >> 2); // 0..127
      int part = l & 3;
      const char* gsrc;
      if (chunk < 2)
        gsrc = (const char*)(Wp + (size_t)(o0 + row)*Cc) + it*128 + chunk*64 + part*16;
      else
        gsrc = (const char*)(Xt + ((size_t)b*Nc + n0 + row)*Cc) + it*128 + (chunk & 1)*64 + part*16;
      load_lds16(gsrc, lds + chunk*8192 + off);
    }
    asm volatile("s_waitcnt vmcnt(0)" ::: "memory");
    __syncthreads();
#pragma unroll
    for (int kc = 0; kc < 2; ++kc){
      f16x8 fw[4], fx[4];
#pragma unroll
      for (int i = 0; i < 4; ++i){
        int wrow = (SW ? (w & 1) : (w >> 1))*64 + i*16 + q;   // o rows
        int xrow = (SW ? (w >> 1) : (w & 1))*64 + i*16 + q;   // n rows
        fw[i] = *(const f16x8*)(lds + kc*8192 + wrow*64 + g*16);
        fx[i] = *(const f16x8*)(lds + 16384 + kc*8192 + xrow*64 + g*16);
      }
#pragma unroll
      for (int i = 0; i < 4; ++i)
#pragma unroll
        for (int jj = 0; jj < 4; ++jj){
          if constexpr (!SW) acc[i][jj] = MFMA16(fw[i], fx[jj], acc[i][jj]); // rows=o, cols=n
          else               acc[i][jj] = MFMA16(fx[i], fw[jj], acc[i][jj]); // rows=n, cols=o
        }
    }
  }

  if constexpr (!SW) {
    f32x4 bias[4];
#pragma unroll
    for (int i = 0; i < 4; ++i) bias[i] = *(const f32x4*)(bb + o0 + (w>>1)*64 + i*16 + 4*g);
#pragma unroll
    for (int i = 0; i < 4; ++i)
#pragma unroll
      for (int jj = 0; jj < 4; ++jj){
        u16x4 pk;
#pragma unroll
        for (int r = 0; r < 4; ++r){
          float z = acc[i][jj][r] + bias[i][r];
          pk[r] = f2h(fmaxf(z, 0.f));
        }
        int o = o0 + (w>>1)*64 + i*16 + 4*g;
        int n = n0 + (w&1)*64 + jj*16 + q;
        int hh = o >> 8, d = o & 255;
        *(u16x4*)(outp + ((size_t)((b*Hc + hh)*Nc + n))*Dc + d) = pk;
      }
  } else {
    float biasv[4];
#pragma unroll
    for (int i = 0; i < 4; ++i) biasv[i] = bb[o0 + (w&1)*64 + i*16 + q];
#pragma unroll
    for (int i = 0; i < 4; ++i)      // nt (rows)
#pragma unroll
      for (int jj = 0; jj < 4; ++jj){ // ot (cols)
        u16x4 pk;
#pragma unroll
        for (int r = 0; r < 4; ++r){
          float z = acc[i][jj][r] + biasv[jj];
          pk[r] = f2h(fmaxf(z, 0.f));
        }
        int o = o0 + (w&1)*64 + jj*16 + q;
        int n = n0 + (w>>1)*64 + i*16 + 4*g;
        int hh = o >> 8, d = o & 255;
        *(u16x4*)(outp + ((size_t)((b*Hc + hh)*Dc + d))*Nc + n) = pk;
      }
  }
}

// ---------------- kernel 2: flash attention ----------------
// block = (b, h, 64 q-rows); 4 waves x 16 q-rows. Swapped QK^T so lane owns one q-col.
__global__ __launch_bounds__(256, 2) void attn_kernel(const u16* __restrict__ Qp,
                                                      const u16* __restrict__ Kp,
                                                      const u16* __restrict__ Vp,
                                                      float* __restrict__ outp){
  // LDS: K 8 chunks [kk][64m][64B] @0..32K ; V half-tile [256d][64B] @32K..48K ; P @48K+
  __shared__ __align__(16) char lds[32768 + 16384 + 4*2304];
  int t = threadIdx.x, w = t >> 6, l = t & 63, q = l & 15, g = l >> 4;
  int qt = blockIdx.x, h = blockIdx.y, b = blockIdx.z;
  int q0 = qt * 64;
  size_t head = (size_t)(b*Hc + h) * Nc * Dc;   // element offset (same for Q,K,V layouts)
  const u16* Kh = Kp + head;
  const u16* Vh = Vp + head;

  // Q fragments (B-operand of swapped QK^T): lane holds row q0+w*16+q of Q
  f16x8 qf[8];
  const u16* qrow = Qp + head + (size_t)(q0 + w*16 + q) * Dc;
#pragma unroll
  for (int kk = 0; kk < 8; ++kk) qf[kk] = *(const f16x8*)(qrow + kk*32 + g*8);

  f32x4 acc_o[16] = {};             // O^T: rows d = 16dt+4g+r, col q
  float m_run = -1e30f, l_run = 0.f;
  char* pbase = lds + 49152 + w*2304;   // per-wave P buffer [16 q][stride 144B]

  for (int kv = 0; kv < 32; ++kv){
    int m0 = kv * 64;
    __syncthreads();
    // stage K tile (32 KB) : 8 insts/wave
#pragma unroll
    for (int j = 0; j < 8; ++j){
      int row = w*16 + (l >> 2);            // 0..63
      const char* gsrc = (const char*)(Kh + (size_t)(m0 + row)*Dc) + j*64 + (l & 3)*16;
      load_lds16(gsrc, lds + j*4096 + w*1024);
    }
    // stage V half-tile kt=0 (16 KB) : 4 insts/wave
#pragma unroll
    for (int j = 0; j < 4; ++j){
      int s = j*4 + w;
      int row = s*16 + (l >> 2);            // d 0..255
      const char* gsrc = (const char*)(Vh + (size_t)row*Nc + m0 + (l & 3)*8);
      load_lds16(gsrc, lds + 32768 + s*1024);
    }
    asm volatile("s_waitcnt vmcnt(0)" ::: "memory");
    __syncthreads();

    // S^T = K · Q^T  (rows m, cols q)
    f32x4 s_acc[4];
#pragma unroll
    for (int mt = 0; mt < 4; ++mt){
      f32x4 a = {0.f, 0.f, 0.f, 0.f};
#pragma unroll
      for (int kk = 0; kk < 8; ++kk){
        f16x8 kf = *(const f16x8*)(lds + kk*4096 + (mt*16 + q)*64 + g*16);
        a = MFMA16(kf, qf[kk], a);
      }
      s_acc[mt] = a;
    }

    // online softmax (lane owns col q; 16 m-values in-lane, rest via xor 16/32)
    float tmax = -1e30f;
#pragma unroll
    for (int mt = 0; mt < 4; ++mt)
#pragma unroll
      for (int r = 0; r < 4; ++r) tmax = fmaxf(tmax, s_acc[mt][r]);
    tmax = fmaxf(tmax, __shfl_xor(tmax, 16));
    tmax = fmaxf(tmax, __shfl_xor(tmax, 32));
    float mnew = fmaxf(m_run, tmax);
    float scale = __expf(m_run - mnew);
    float rsum = 0.f;
#pragma unroll
    for (int mt = 0; mt < 4; ++mt){
      u16x4 pk;
#pragma unroll
      for (int r = 0; r < 4; ++r){
        float p = __expf(s_acc[mt][r] - mnew);
        rsum += p;
        pk[r] = f2h(p);
      }
      *(u16x4*)(pbase + q*144 + (mt*16 + 4*g)*2) = pk;   // P[q][m], m = 16mt+4g+r
    }
    rsum += __shfl_xor(rsum, 16);
    rsum += __shfl_xor(rsum, 32);
    l_run = l_run * scale + rsum;
    m_run = mnew;
#pragma unroll
    for (int dt = 0; dt < 16; ++dt) acc_o[dt] *= scale;

    // P fragments (B-operand of PV): lane reads its q-row, 8 contiguous m
    f16x8 pb0 = *(const f16x8*)(pbase + q*144 + g*16);
    f16x8 pb1 = *(const f16x8*)(pbase + q*144 + 64 + g*16);

    // PV half 1: O^T += V^T(kt0) · P^T
#pragma unroll
    for (int dt = 0; dt < 16; ++dt){
      f16x8 vf = *(const f16x8*)(lds + 32768 + (dt*16 + q)*64 + g*16);
      acc_o[dt] = MFMA16(vf, pb0, acc_o[dt]);
    }
    __syncthreads();
    // stage V half-tile kt=1 into same buffer
#pragma unroll
    for (int j = 0; j < 4; ++j){
      int s = j*4 + w;
      int row = s*16 + (l >> 2);
      const char* gsrc = (const char*)(Vh + (size_t)row*Nc + m0 + 32 + (l & 3)*8);
      load_lds16(gsrc, lds + 32768 + s*1024);
    }
    asm volatile("s_waitcnt vmcnt(0)" ::: "memory");
    __syncthreads();
#pragma unroll
    for (int dt = 0; dt < 16; ++dt){
      f16x8 vf = *(const f16x8*)(lds + 32768 + (dt*16 + q)*64 + g*16);
      acc_o[dt] = MFMA16(vf, pb1, acc_o[dt]);
    }
  }

  float inv = 1.f / l_run;
  size_t obase = ((size_t)(b*Hc + h)*Nc + q0 + w*16 + q) * Dc;
#pragma unroll
  for (int dt = 0; dt < 16; ++dt){
    f32x4 v = acc_o[dt] * inv;
    *(f32x4*)(outp + obase + dt*16 + 4*g) = v;
  }
}

// ---------------- launch ----------------
extern "C" void kernel_launch(void* const* d_in, const int* in_sizes, int n_in,
                              void* d_out, int out_size, void* d_ws, size_t ws_size,
                              hipStream_t stream){
  const float* x     = (const float*)d_in[0];
  const float* y     = (const float*)d_in[1];
  const float* Wq    = (const float*)d_in[2];
  const float* bq    = (const float*)d_in[3];
  const float* gq    = (const float*)d_in[4];
  const float* betaq = (const float*)d_in[5];
  const float* Wk    = (const float*)d_in[6];
  const float* bk    = (const float*)d_in[7];
  const float* gk    = (const float*)d_in[8];
  const float* betak = (const float*)d_in[9];
  const float* Wv    = (const float*)d_in[10];
  const float* bv    = (const float*)d_in[11];
  const float* gv    = (const float*)d_in[12];
  const float* betav = (const float*)d_in[13];
  char* ws = (char*)d_ws;
  float* outp = (float*)d_out;

  u16* XT = (u16*)(ws + OFF_XT);
  u16* YT = (u16*)(ws + OFF_YT);
  u16* WQb = (u16*)(ws + OFF_WQ);
  u16* WKb = (u16*)(ws + OFF_WK);
  u16* WVb = (u16*)(ws + OFF_WV);
  float* BQ = (float*)(ws + OFF_BQ);
  float* BK = (float*)(ws + OFF_BK);
  float* BV = (float*)(ws + OFF_BV);
  u16* Qw = (u16*)(ws + OFF_Q);
  u16* Kw = (u16*)(ws + OFF_K);
  u16* Vw = (u16*)(ws + OFF_V);

  transpose_cast<<<dim3(Nc/64, Cc/64, Bc*2), 256, 0, stream>>>(x, y, XT, YT);
  prep_w<<<dim3(OCc*Cc/2048), 256, 0, stream>>>(Wq, bq, gq, betaq, WQb, BQ);
  prep_w<<<dim3(OCc*Cc/2048), 256, 0, stream>>>(Wk, bk, gk, betak, WKb, BK);
  prep_w<<<dim3(OCc*Cc/2048), 256, 0, stream>>>(Wv, bv, gv, betav, WVb, BV);

  dim3 pg(Nc/128, OCc/128, Bc);
  proj_gemm<0><<<pg, 256, 0, stream>>>(XT, WQb, BQ, Qw);
  proj_gemm<0><<<pg, 256, 0, stream>>>(YT, WKb, BK, Kw);
  proj_gemm<1><<<pg, 256, 0, stream>>>(YT, WVb, BV, Vw);

  attn_kernel<<<dim3(Nc/64, Hc, Bc), 256, 0, stream>>>(Qw, Kw, Vw, outp);
}